// Round 7
// baseline (692.029 us; speedup 1.0000x reference)
//
#include <hip/hip_runtime.h>
#include <math.h>

#define B_ 16
#define N_ 2048
#define D_ 64
#define BT 32    // n-rows per workgroup
#define MT 128   // m-cols per tile
#define QS 68    // LDS strides: odd multiple of 16B -> 0 bank conflicts (measured R2-R6)
#define KS 68

// ---------------------------------------------------------------------------
// Kernel 0: detect mask element size (bool may arrive as int32 or uint8).
// Also zeroes the tie counter. R2-R6 FETCH evidence says uint8 here, but
// detection costs ~2 us and keeps us correct either way.
// ---------------------------------------------------------------------------
__global__ __launch_bounds__(256) void attn_detect(const unsigned int* __restrict__ mask,
                                                   int* __restrict__ flag,
                                                   int* __restrict__ tie_counter) {
    __shared__ int bad;
    if (threadIdx.x == 0) bad = 0;
    __syncthreads();
    unsigned int w = mask[threadIdx.x] | mask[threadIdx.x + 256] |
                     mask[threadIdx.x + 512] | mask[threadIdx.x + 768];
    if (w > 1u) bad = 1;
    __syncthreads();
    if (threadIdx.x == 0) { *flag = bad ? 1 : 4; *tie_counter = 0; }
}

// ---------------------------------------------------------------------------
// Kernel 0b: zero-fill attn. (R5 memset-SDMA was slow; R6 gap analysis shows
// this fill is largely hidden under fixed harness overhead.)
// ---------------------------------------------------------------------------
__global__ __launch_bounds__(256) void attn_fill(float4* __restrict__ p, long long n4) {
    const float4 z = make_float4(0.f, 0.f, 0.f, 0.f);
    long long i = (long long)blockIdx.x * 256 + threadIdx.x;
    const long long stride = (long long)gridDim.x * 256;
    for (; i < n4; i += stride) p[i] = z;
}

// ---------------------------------------------------------------------------
// Kernel 1: main pass. Per block: 32 q-rows vs all 2048 k-rows of one batch.
// 4x4 micro-tile + register prefetch of the next K tile.
// Occupancy knob history (this toolchain lowers the "min waves" arg ~2x):
//   (256,3) [R3] -> 84 VGPR  -> acc spill, 6 ms   NEVER
//   waves_per_eu(3) [R4] -> 84 VGPR -> same        NEVER
//   waves_per_eu(2) [R6] -> 68 VGPR -> pf spill (~400 MB scratch) but 334 us
//   (256,2) [R7] -> expect 128 VGPR: fits acc16+pf32+qkv32+misc -> no spill.
//   Benign failure: lowers to 256 = R5 behavior.
// Argmax/tie tracking on raw fp32 'acc' (monotone transform of reference's
// (u/8)/1e-14; structural ties identical — absmax 0.0 in R3-R6).
// ---------------------------------------------------------------------------
__global__ __launch_bounds__(256, 2)
void attn_main(const float* __restrict__ q,
               const float* __restrict__ k,
               const float* __restrict__ v,
               const void* __restrict__ maskp,
               float* __restrict__ attn,
               float* __restrict__ outp,
               const int* __restrict__ flagp,
               int* __restrict__ tie_counter,
               int* __restrict__ tie_recs) {
    const int flag = flagp ? *flagp : 4;   // 4 = int32 mask, 1 = uint8 mask
    const int tile = blockIdx.x;           // 1024 blocks = 16 batches * 64 row-tiles
    const int b    = tile >> 6;
    const int n0   = (tile & 63) * BT;
    const int tid  = threadIdx.x;
    const int tx   = tid & 31;             // m direction (owns m = m0 + tx + 32j)
    const int ty   = tid >> 5;             // n direction (owns rows ty*4 + i)
    const int ty4  = ty * 4;

    __shared__ float qs[BT][QS];
    __shared__ float ks[MT][KS];

    // staging geometry: row = fid>>4; col4 = (fid&15)*4
    const int srow = tid >> 4;             // 0..15
    const int scol = (tid & 15) * 4;       // 0..60

    // ---- stage q tile (32 x 64) ----
    {
        const float* qbase = q + ((size_t)b * N_ + n0) * D_;
        #pragma unroll
        for (int it = 0; it < 2; ++it) {
            int r = srow + 16 * it;
            *(float4*)&qs[r][scol] = *(const float4*)(qbase + r * D_ + scol);
        }
    }

    float lmax[4];
    int   lcnt[4], lpos[4];
    #pragma unroll
    for (int i = 0; i < 4; ++i) { lmax[i] = -INFINITY; lcnt[i] = 0; lpos[i] = 0; }

    const int* __restrict__ mask_i32 = (const int*)maskp;
    const unsigned char* __restrict__ mask_u8 = (const unsigned char*)maskp;
    const size_t rowbase = (size_t)b * N_ + n0;   // first global row of this block

    // ---- prefetch K tile 0 into registers ----
    const float* kbatch = k + (size_t)b * N_ * D_;
    float4 pf[8];
    #pragma unroll
    for (int it = 0; it < 8; ++it)
        pf[it] = *(const float4*)(kbatch + (size_t)(srow + 16 * it) * D_ + scol);

    #pragma unroll 1
    for (int mt = 0; mt < N_ / MT; ++mt) {
        const int m0 = mt * MT;
        __syncthreads();   // previous tile's LDS readers done before overwrite

        // ---- commit prefetched K tile to LDS ----
        #pragma unroll
        for (int it = 0; it < 8; ++it)
            *(float4*)&ks[srow + 16 * it][scol] = pf[it];

        // ---- issue prefetch of NEXT K tile (consumed next iteration) ----
        if (mt + 1 < N_ / MT) {
            const float* kb = kbatch + (size_t)(m0 + MT) * D_;
            #pragma unroll
            for (int it = 0; it < 8; ++it)
                pf[it] = *(const float4*)(kb + (size_t)(srow + 16 * it) * D_ + scol);
        }

        // ---- mask loads for this tile (consumed after compute) ----
        unsigned char mk[4][4];
        if (flag == 4) {
            #pragma unroll
            for (int i = 0; i < 4; ++i) {
                const int* mrow = mask_i32 + (rowbase + ty4 + i) * N_ + m0;
                #pragma unroll
                for (int j = 0; j < 4; ++j)
                    mk[i][j] = (unsigned char)(__builtin_nontemporal_load(mrow + tx + 32 * j) != 0);
            }
        } else {
            #pragma unroll
            for (int i = 0; i < 4; ++i) {
                const unsigned char* mrow = mask_u8 + (rowbase + ty4 + i) * N_ + m0;
                #pragma unroll
                for (int j = 0; j < 4; ++j)
                    mk[i][j] = (unsigned char)(__builtin_nontemporal_load(mrow + tx + 32 * j) != 0);
            }
        }

        __syncthreads();   // k tile visible

        // ---- 4x4 micro-tile FMA over d (ascending single chain per pair) ----
        float acc[4][4];
        #pragma unroll
        for (int i = 0; i < 4; ++i)
            #pragma unroll
            for (int j = 0; j < 4; ++j) acc[i][j] = 0.0f;

        #pragma unroll 4
        for (int d = 0; d < D_; d += 4) {
            float4 qv[4], kv[4];
            #pragma unroll
            for (int i = 0; i < 4; ++i) qv[i] = *(const float4*)&qs[ty4 + i][d];
            #pragma unroll
            for (int j = 0; j < 4; ++j) kv[j] = *(const float4*)&ks[tx + 32 * j][d];
            #pragma unroll
            for (int i = 0; i < 4; ++i)
                #pragma unroll
                for (int j = 0; j < 4; ++j) {
                    acc[i][j] = fmaf(qv[i].x, kv[j].x, acc[i][j]);
                    acc[i][j] = fmaf(qv[i].y, kv[j].y, acc[i][j]);
                    acc[i][j] = fmaf(qv[i].z, kv[j].z, acc[i][j]);
                    acc[i][j] = fmaf(qv[i].w, kv[j].w, acc[i][j]);
                }
        }

        // ---- mask + running (max, count, pos) on raw acc ----
        #pragma unroll
        for (int j = 0; j < 4; ++j) {
            int m = m0 + tx + 32 * j;
            #pragma unroll
            for (int i = 0; i < 4; ++i) {
                float cand = mk[i][j] ? -INFINITY : acc[i][j];
                if (cand > lmax[i])       { lmax[i] = cand; lcnt[i] = 1; lpos[i] = m; }
                else if (cand == lmax[i]) { lcnt[i]++; }
            }
        }
    }

    // ---- butterfly-reduce across the 32 tx lanes, then epilogue per row ----
    #pragma unroll
    for (int i = 0; i < 4; ++i) {
        float m_ = lmax[i];
        int   c_ = lcnt[i];
        int   p_ = lpos[i];
        #pragma unroll
        for (int off = 16; off >= 1; off >>= 1) {
            float om = __shfl_xor(m_, off);
            int   oc = __shfl_xor(c_, off);
            int   op = __shfl_xor(p_, off);
            if (om > m_)       { m_ = om; c_ = oc; p_ = op; }
            else if (om == m_) { c_ += oc; p_ = min(p_, op); }
        }
        const size_t row = rowbase + ty4 + i;
        if (tx == 0) {
            if (c_ == 1) {
                attn[row * N_ + p_] = 1.0f;
            } else if (c_ > 1) {
                if (tie_recs) {
                    int s = atomicAdd(tie_counter, 1);
                    tie_recs[3 * s]     = (int)row;
                    tie_recs[3 * s + 1] = c_;
                    tie_recs[3 * s + 2] = __float_as_int(m_);
                } else {
                    attn[row * N_ + p_] = 1.0f / (float)c_;  // best effort, no workspace
                }
            }
        }
        float* orow = outp + row * D_;
        if (c_ == 1) {
            const float* vrow = v + ((size_t)b * N_ + p_) * D_;
            orow[tx]      = vrow[tx];
            orow[tx + 32] = vrow[tx + 32];
        } else {
            orow[tx]      = 0.0f;   // c_>1 rows overwritten by kernel 2
            orow[tx + 32] = 0.0f;
        }
    }
}

// ---------------------------------------------------------------------------
// Kernel 2: exact-tie fixup (expected ~0-2 rows total). Recomputes the row
// with a bitwise-identical fmaf chain on raw acc, writes 1/count at tie
// positions and the averaged v-row. Blocks with no work exit immediately.
// ---------------------------------------------------------------------------
__global__ __launch_bounds__(64) void attn_tiefix(const float* __restrict__ q,
                                                  const float* __restrict__ k,
                                                  const float* __restrict__ v,
                                                  const void* __restrict__ maskp,
                                                  float* __restrict__ attn,
                                                  float* __restrict__ outp,
                                                  const int* __restrict__ flagp,
                                                  const int* __restrict__ tie_counter,
                                                  const int* __restrict__ tie_recs) {
    const int ntie = *tie_counter;
    if (ntie == 0) return;
    const int flag = *flagp;
    const int lane = threadIdx.x;
    __shared__ float qrow[D_];
    __shared__ int tie_m[N_];
    __shared__ int ntm;

    for (int idx = blockIdx.x; idx < ntie; idx += gridDim.x) {
        const int   row = tie_recs[3 * idx];
        const int   cnt = tie_recs[3 * idx + 1];
        const float mx  = __int_as_float(tie_recs[3 * idx + 2]);
        const int   b   = row >> 11;
        __syncthreads();               // guard LDS reuse across idx iterations
        if (lane == 0) ntm = 0;
        qrow[lane] = q[(size_t)row * D_ + lane];
        __syncthreads();
        const float inv = 1.0f / (float)cnt;
        for (int mb = 0; mb < N_; mb += 64) {
            const int m = mb + lane;
            bool msk = (flag == 4) ? (((const int*)maskp)[(size_t)row * N_ + m] != 0)
                                   : (((const unsigned char*)maskp)[(size_t)row * N_ + m] != 0);
            const float* kr = k + ((size_t)b * N_ + m) * D_;
            float u = 0.0f;
            #pragma unroll
            for (int d = 0; d < D_; d += 4) {   // same ascending chain as kernel 1
                float4 kv = *(const float4*)(kr + d);
                u = fmaf(qrow[d],     kv.x, u);
                u = fmaf(qrow[d + 1], kv.y, u);
                u = fmaf(qrow[d + 2], kv.z, u);
                u = fmaf(qrow[d + 3], kv.w, u);
            }
            if (!msk && u == mx) {
                attn[(size_t)row * N_ + m] = inv;
                int s = atomicAdd(&ntm, 1);
                tie_m[s] = m;
            }
        }
        __syncthreads();
        float sv = 0.0f;
        const int c2 = ntm;
        for (int t2 = 0; t2 < c2; ++t2)
            sv += v[((size_t)b * N_ + tie_m[t2]) * D_ + lane];
        outp[(size_t)row * D_ + lane] = sv * inv;
    }
}

extern "C" void kernel_launch(void* const* d_in, const int* in_sizes, int n_in,
                              void* d_out, int out_size, void* d_ws, size_t ws_size,
                              hipStream_t stream) {
    const float* q    = (const float*)d_in[0];
    const float* k    = (const float*)d_in[1];
    const float* v    = (const float*)d_in[2];
    const void*  mask = d_in[3];
    float* attn = (float*)d_out;
    float* outp = attn + (size_t)B_ * N_ * N_;   // attn [16,2048,2048] then output [16,2048,64]

    // zero-fill the attn plane with a kernel; main kernel writes only
    // the one-hot entries on top of it (stream-ordered).
    attn_fill<<<2048, 256, 0, stream>>>((float4*)attn,
                                        (long long)B_ * N_ * N_ / 4);

    // workspace layout: [0] flag, [16] tie counter, [64] tie records (3 ints x 32768)
    const size_t need = 64 + (size_t)3 * (B_ * N_) * sizeof(int);
    const bool full     = ws_size >= need;
    const bool haveflag = ws_size >= 32;
    int* flag = (int*)d_ws;
    int* tiec = (int*)((char*)d_ws + 16);
    int* tier = (int*)((char*)d_ws + 64);

    if (haveflag)
        attn_detect<<<1, 256, 0, stream>>>((const unsigned int*)mask, flag, tiec);

    attn_main<<<(B_ * N_) / BT, 256, 0, stream>>>(
        q, k, v, mask, attn, outp,
        haveflag ? flag : nullptr,
        full ? tiec : nullptr,
        full ? tier : nullptr);

    if (full)
        attn_tiefix<<<64, 64, 0, stream>>>(q, k, v, mask, attn, outp, flag, tiec, tier);
}

// Round 8
// 616.521 us; speedup vs baseline: 1.1225x; 1.1225x over previous
//
#include <hip/hip_runtime.h>
#include <math.h>

#define B_ 16
#define N_ 2048
#define D_ 64
#define BT 32    // n-rows per workgroup
#define MT 128   // m-cols per tile

typedef const float __attribute__((address_space(1)))* gas_fp;  // global
typedef float __attribute__((address_space(3)))* las_fp;        // LDS

// ---------------------------------------------------------------------------
// Kernel 0: detect mask element size (bool may arrive as int32 or uint8).
// Also zeroes the tie counter. R2-R7 FETCH evidence says uint8 here, but
// detection costs ~2 us and keeps us correct either way.
// ---------------------------------------------------------------------------
__global__ __launch_bounds__(256) void attn_detect(const unsigned int* __restrict__ mask,
                                                   int* __restrict__ flag,
                                                   int* __restrict__ tie_counter) {
    __shared__ int bad;
    if (threadIdx.x == 0) bad = 0;
    __syncthreads();
    unsigned int w = mask[threadIdx.x] | mask[threadIdx.x + 256] |
                     mask[threadIdx.x + 512] | mask[threadIdx.x + 768];
    if (w > 1u) bad = 1;
    __syncthreads();
    if (threadIdx.x == 0) { *flag = bad ? 1 : 4; *tie_counter = 0; }
}

// ---------------------------------------------------------------------------
// Kernel 0b: zero-fill attn (268 MB) at HBM write BW (~55 us).
// ---------------------------------------------------------------------------
__global__ __launch_bounds__(256) void attn_fill(float4* __restrict__ p, long long n4) {
    const float4 z = make_float4(0.f, 0.f, 0.f, 0.f);
    long long i = (long long)blockIdx.x * 256 + threadIdx.x;
    const long long stride = (long long)gridDim.x * 256;
    for (; i < n4; i += stride) p[i] = z;
}

// ---------------------------------------------------------------------------
// Kernel 1: main pass. 32 q-rows vs all 2048 k-rows of one batch per block.
// 4x4 micro-tile. K staged via async global_load_lds (width 16) into a
// DOUBLE-BUFFERED unpadded LDS tile with XOR chunk swizzle (slot=cj^(row&15))
// applied on the global-address side (DMA dest is wave-uniform+lane*16, so
// no padding possible). Q staged once, unpadded (reads are broadcast).
// NO occupancy attributes: every variant tried ((256,3),(256,2),
// waves_per_eu(2/3)) lowers to a 68-84 VGPR cap -> spill -> 400MB-19GB
// scratch traffic [R3,R4,R6,R7]. LDS=72KB caps at 2 blocks/CU instead.
// Argmax/tie tracking on raw fp32 'acc' (monotone transform of reference's
// (u/8)/1e-14; structural ties identical — absmax 0.0 in R3-R7).
// ---------------------------------------------------------------------------
__global__ __launch_bounds__(256)
void attn_main(const float* __restrict__ q,
               const float* __restrict__ k,
               const float* __restrict__ v,
               const void* __restrict__ maskp,
               float* __restrict__ attn,
               float* __restrict__ outp,
               const int* __restrict__ flagp,
               int* __restrict__ tie_counter,
               int* __restrict__ tie_recs) {
    const int flag = flagp ? *flagp : 4;   // 4 = int32 mask, 1 = uint8 mask
    const int tile = blockIdx.x;           // 1024 blocks = 16 batches * 64 row-tiles
    const int b    = tile >> 6;
    const int n0   = (tile & 63) * BT;
    const int tid  = threadIdx.x;
    const int tx   = tid & 31;             // m direction (owns m = m0 + tx + 32j)
    const int ty   = tid >> 5;             // n direction (owns rows ty*4 + i)
    const int ty4  = ty * 4;
    const int wv   = tid >> 6;             // wave id 0..3
    const int ln   = tid & 63;             // lane id
    const int lrow = ln >> 4;              // 0..3   (row within a 4-row DMA call)
    const int lcs  = ln & 15;              // chunk slot within row
    const int txl  = tx & 15;              // read-side swizzle key

    __shared__ float ks[2][MT * D_];       // 2 x 32 KB, swizzled chunks
    __shared__ float qs[BT * D_];          // 8 KB, row-major

    const float* qbase  = q + ((size_t)b * N_ + n0) * D_;
    const float* kbatch = k + (size_t)b * N_ * D_;

    // ---- issue async Q staging (2 calls/wave: 8 rows) ----
    #pragma unroll
    for (int it = 0; it < 2; ++it) {
        const int R   = wv * 8 + it * 4;
        const int row = R + lrow;
        __builtin_amdgcn_global_load_lds((gas_fp)(qbase + row * D_ + lcs * 4),
                                         (las_fp)&qs[R * D_], 16, 0, 0);
    }
    // ---- issue async K tile 0 into buf 0 (8 calls/wave: 32 rows/wave) ----
    #pragma unroll
    for (int it = 0; it < 8; ++it) {
        const int R     = wv * 32 + it * 4;
        const int row   = R + lrow;
        const int cglob = lcs ^ (row & 15);               // inverse of read swizzle
        __builtin_amdgcn_global_load_lds((gas_fp)(kbatch + row * D_ + cglob * 4),
                                         (las_fp)&ks[0][R * D_], 16, 0, 0);
    }

    float lmax[4];
    int   lcnt[4], lpos[4];
    #pragma unroll
    for (int i = 0; i < 4; ++i) { lmax[i] = -INFINITY; lcnt[i] = 0; lpos[i] = 0; }

    const int* __restrict__ mask_i32 = (const int*)maskp;
    const unsigned char* __restrict__ mask_u8 = (const unsigned char*)maskp;
    const size_t rowbase = (size_t)b * N_ + n0;   // first global row of this block

    __syncthreads();   // drain q + k-tile-0 DMA (vmcnt(0) before barrier)

    #pragma unroll 1
    for (int mt = 0; mt < N_ / MT; ++mt) {
        const int m0  = mt * MT;
        const int cur = mt & 1;

        // ---- issue async K tile mt+1 into the other buffer ----
        if (mt + 1 < N_ / MT) {
            const float* kb = kbatch + (size_t)(m0 + MT) * D_;
            #pragma unroll
            for (int it = 0; it < 8; ++it) {
                const int R     = wv * 32 + it * 4;
                const int row   = R + lrow;
                const int cglob = lcs ^ (row & 15);
                __builtin_amdgcn_global_load_lds((gas_fp)(kb + row * D_ + cglob * 4),
                                                 (las_fp)&ks[1 - cur][R * D_], 16, 0, 0);
            }
        }

        // ---- mask loads for this tile (consumed after compute) ----
        unsigned char mk[4][4];
        if (flag == 4) {
            #pragma unroll
            for (int i = 0; i < 4; ++i) {
                const int* mrow = mask_i32 + (rowbase + ty4 + i) * N_ + m0;
                #pragma unroll
                for (int j = 0; j < 4; ++j)
                    mk[i][j] = (unsigned char)(__builtin_nontemporal_load(mrow + tx + 32 * j) != 0);
            }
        } else {
            #pragma unroll
            for (int i = 0; i < 4; ++i) {
                const unsigned char* mrow = mask_u8 + (rowbase + ty4 + i) * N_ + m0;
                #pragma unroll
                for (int j = 0; j < 4; ++j)
                    mk[i][j] = (unsigned char)(__builtin_nontemporal_load(mrow + tx + 32 * j) != 0);
            }
        }

        // ---- 4x4 micro-tile FMA over d (ascending single chain per pair) ----
        const float* ksb = &ks[cur][0];
        float acc[4][4];
        #pragma unroll
        for (int i = 0; i < 4; ++i)
            #pragma unroll
            for (int j = 0; j < 4; ++j) acc[i][j] = 0.0f;

        #pragma unroll 4
        for (int d = 0; d < D_; d += 4) {
            const int sw = (((d >> 2) ^ txl) << 2);      // swizzled chunk offset
            float4 qv[4], kv[4];
            #pragma unroll
            for (int i = 0; i < 4; ++i) qv[i] = *(const float4*)&qs[(ty4 + i) * D_ + d];
            #pragma unroll
            for (int j = 0; j < 4; ++j) kv[j] = *(const float4*)&ksb[(tx + 32 * j) * D_ + sw];
            #pragma unroll
            for (int i = 0; i < 4; ++i)
                #pragma unroll
                for (int j = 0; j < 4; ++j) {
                    acc[i][j] = fmaf(qv[i].x, kv[j].x, acc[i][j]);
                    acc[i][j] = fmaf(qv[i].y, kv[j].y, acc[i][j]);
                    acc[i][j] = fmaf(qv[i].z, kv[j].z, acc[i][j]);
                    acc[i][j] = fmaf(qv[i].w, kv[j].w, acc[i][j]);
                }
        }

        // ---- mask + running (max, count, pos) on raw acc ----
        #pragma unroll
        for (int j = 0; j < 4; ++j) {
            int m = m0 + tx + 32 * j;
            #pragma unroll
            for (int i = 0; i < 4; ++i) {
                float cand = mk[i][j] ? -INFINITY : acc[i][j];
                if (cand > lmax[i])       { lmax[i] = cand; lcnt[i] = 1; lpos[i] = m; }
                else if (cand == lmax[i]) { lcnt[i]++; }
            }
        }

        __syncthreads();   // drain next-tile DMA + this tile's ds_reads
    }

    // ---- butterfly-reduce across the 32 tx lanes, then epilogue per row ----
    #pragma unroll
    for (int i = 0; i < 4; ++i) {
        float m_ = lmax[i];
        int   c_ = lcnt[i];
        int   p_ = lpos[i];
        #pragma unroll
        for (int off = 16; off >= 1; off >>= 1) {
            float om = __shfl_xor(m_, off);
            int   oc = __shfl_xor(c_, off);
            int   op = __shfl_xor(p_, off);
            if (om > m_)       { m_ = om; c_ = oc; p_ = op; }
            else if (om == m_) { c_ += oc; p_ = min(p_, op); }
        }
        const size_t row = rowbase + ty4 + i;
        if (tx == 0) {
            if (c_ == 1) {
                attn[row * N_ + p_] = 1.0f;
            } else if (c_ > 1) {
                if (tie_recs) {
                    int s = atomicAdd(tie_counter, 1);
                    tie_recs[3 * s]     = (int)row;
                    tie_recs[3 * s + 1] = c_;
                    tie_recs[3 * s + 2] = __float_as_int(m_);
                } else {
                    attn[row * N_ + p_] = 1.0f / (float)c_;  // best effort, no workspace
                }
            }
        }
        float* orow = outp + row * D_;
        if (c_ == 1) {
            const float* vrow = v + ((size_t)b * N_ + p_) * D_;
            orow[tx]      = vrow[tx];
            orow[tx + 32] = vrow[tx + 32];
        } else {
            orow[tx]      = 0.0f;   // c_>1 rows overwritten by kernel 2
            orow[tx + 32] = 0.0f;
        }
    }
}

// ---------------------------------------------------------------------------
// Kernel 2: exact-tie fixup (expected ~0-2 rows total). Recomputes the row
// with a bitwise-identical fmaf chain on raw acc, writes 1/count at tie
// positions and the averaged v-row. Blocks with no work exit immediately.
// ---------------------------------------------------------------------------
__global__ __launch_bounds__(64) void attn_tiefix(const float* __restrict__ q,
                                                  const float* __restrict__ k,
                                                  const float* __restrict__ v,
                                                  const void* __restrict__ maskp,
                                                  float* __restrict__ attn,
                                                  float* __restrict__ outp,
                                                  const int* __restrict__ flagp,
                                                  const int* __restrict__ tie_counter,
                                                  const int* __restrict__ tie_recs) {
    const int ntie = *tie_counter;
    if (ntie == 0) return;
    const int flag = *flagp;
    const int lane = threadIdx.x;
    __shared__ float qrow[D_];
    __shared__ int tie_m[N_];
    __shared__ int ntm;

    for (int idx = blockIdx.x; idx < ntie; idx += gridDim.x) {
        const int   row = tie_recs[3 * idx];
        const int   cnt = tie_recs[3 * idx + 1];
        const float mx  = __int_as_float(tie_recs[3 * idx + 2]);
        const int   b   = row >> 11;
        __syncthreads();               // guard LDS reuse across idx iterations
        if (lane == 0) ntm = 0;
        qrow[lane] = q[(size_t)row * D_ + lane];
        __syncthreads();
        const float inv = 1.0f / (float)cnt;
        for (int mb = 0; mb < N_; mb += 64) {
            const int m = mb + lane;
            bool msk = (flag == 4) ? (((const int*)maskp)[(size_t)row * N_ + m] != 0)
                                   : (((const unsigned char*)maskp)[(size_t)row * N_ + m] != 0);
            const float* kr = k + ((size_t)b * N_ + m) * D_;
            float u = 0.0f;
            #pragma unroll
            for (int d = 0; d < D_; d += 4) {   // same ascending chain as kernel 1
                float4 kv = *(const float4*)(kr + d);
                u = fmaf(qrow[d],     kv.x, u);
                u = fmaf(qrow[d + 1], kv.y, u);
                u = fmaf(qrow[d + 2], kv.z, u);
                u = fmaf(qrow[d + 3], kv.w, u);
            }
            if (!msk && u == mx) {
                attn[(size_t)row * N_ + m] = inv;
                int s = atomicAdd(&ntm, 1);
                tie_m[s] = m;
            }
        }
        __syncthreads();
        float sv = 0.0f;
        const int c2 = ntm;
        for (int t2 = 0; t2 < c2; ++t2)
            sv += v[((size_t)b * N_ + tie_m[t2]) * D_ + lane];
        outp[(size_t)row * D_ + lane] = sv * inv;
    }
}

extern "C" void kernel_launch(void* const* d_in, const int* in_sizes, int n_in,
                              void* d_out, int out_size, void* d_ws, size_t ws_size,
                              hipStream_t stream) {
    const float* q    = (const float*)d_in[0];
    const float* k    = (const float*)d_in[1];
    const float* v    = (const float*)d_in[2];
    const void*  mask = d_in[3];
    float* attn = (float*)d_out;
    float* outp = attn + (size_t)B_ * N_ * N_;   // attn [16,2048,2048] then output [16,2048,64]

    // zero-fill the attn plane; main kernel writes only one-hot entries.
    attn_fill<<<2048, 256, 0, stream>>>((float4*)attn,
                                        (long long)B_ * N_ * N_ / 4);

    // workspace layout: [0] flag, [16] tie counter, [64] tie records (3 ints x 32768)
    const size_t need = 64 + (size_t)3 * (B_ * N_) * sizeof(int);
    const bool full     = ws_size >= need;
    const bool haveflag = ws_size >= 32;
    int* flag = (int*)d_ws;
    int* tiec = (int*)((char*)d_ws + 16);
    int* tier = (int*)((char*)d_ws + 64);

    if (haveflag)
        attn_detect<<<1, 256, 0, stream>>>((const unsigned int*)mask, flag, tiec);

    attn_main<<<(B_ * N_) / BT, 256, 0, stream>>>(
        q, k, v, mask, attn, outp,
        haveflag ? flag : nullptr,
        full ? tiec : nullptr,
        full ? tier : nullptr);

    if (full)
        attn_tiefix<<<64, 64, 0, stream>>>(q, k, v, mask, attn, outp, flag, tiec, tier);
}